// Round 2
// baseline (1455.746 us; speedup 1.0000x reference)
//
#include <hip/hip_runtime.h>
#include <hip/hip_bf16.h>

// ---------------------------------------------------------------------------
// RNN_17214228922840: GraphRNN-ish model. fp32 I/O, bf16 MFMA compute.
//   B=128, TV=32, TE=64, VOCAB=1024, EMB=256, H=512 (3H=1536), REPR=128, NET=8
// Outputs (flat, fp32): O_vertex [128,1024,32] | O_edge [128,32,2,64] | O_edge_type [128,8,64]
// ---------------------------------------------------------------------------

typedef __bf16 bf16_t;
typedef bf16_t bf16x8 __attribute__((ext_vector_type(8)));
typedef bf16_t bf16x4 __attribute__((ext_vector_type(4)));
typedef float  f32x4  __attribute__((ext_vector_type(4)));

// workspace layout (bf16 element offsets)
#define OFF_GIV  0ull                    // 32*128*1536
#define OFF_GIE  6291456ull              // 64*128*1536
#define OFF_HV   18874368ull             // 32*128*512
#define OFF_HE   20971520ull             // 64*128*512
#define OFF_VREP 25165824ull             // 32*128*128
#define OFF_EREP 25690112ull             // 64*128*128
#define OFF_HBUF 26738688ull             // 16 slots * 2 parity * 8192
#define CNT_BYTE_OFF 54001664ull         // 1024 ints (16 counters, 64 apart)
#define OFF_CVT  27002880ull             // converted bf16 weights below
#define CVT_VEMB  0ull
#define CVT_EEMB  262144ull
#define CVT_VWI   270336ull
#define CVT_EWI   663552ull
#define CVT_VWH   1449984ull
#define CVT_EWH   2236416ull
#define CVT_VOUT  3022848ull
#define CVT_VREPW 3547136ull
#define CVT_EREPW 3612672ull
// total ws use: (27002880+3678208)*2 = 61,362,176 bytes

// output flat offsets (fp32 elements)
#define OUT_OV 0ull
#define OUT_OE 4194304ull
#define OUT_OT 4718592ull

__device__ __forceinline__ float fsigmoid(float x) {
    float e = __builtin_amdgcn_exp2f(-x * 1.4426950408889634f);
    return __builtin_amdgcn_rcpf(1.0f + e);
}
__device__ __forceinline__ float ftanh(float x) {
    x = fminf(x, 15.0f);
    float e = __builtin_amdgcn_exp2f(x * 2.8853900817779268f); // exp(2x)
    return (e - 1.0f) * __builtin_amdgcn_rcpf(e + 1.0f);
}

// ---------------------------------------------------------------------------
// prep: fp32 -> bf16 downcast of weights/embeddings (blocks 0..3591, 1024 elem
// per block) + zero hbuf/counters (blocks 3592..3720, 1024 ints per block).
// ---------------------------------------------------------------------------
__global__ __launch_bounds__(256) void prep_kernel(
    const float* __restrict__ vemb, const float* __restrict__ eemb,
    const float* __restrict__ vwi,  const float* __restrict__ ewi,
    const float* __restrict__ vwh,  const float* __restrict__ ewh,
    const float* __restrict__ voutw, const float* __restrict__ vrepw,
    const float* __restrict__ erepw, bf16_t* __restrict__ cvt,
    int* __restrict__ zero_base)
{
    int blk = blockIdx.x;
    if (blk >= 3592) {
        ((int4*)zero_base)[(blk - 3592) * 256 + threadIdx.x] = (int4){0, 0, 0, 0};
        return;
    }
    const float* src; bf16_t* dst; int lb;
    if (blk < 256)       { src = vemb;  dst = cvt + CVT_VEMB;  lb = blk; }
    else if (blk < 264)  { src = eemb;  dst = cvt + CVT_EEMB;  lb = blk - 256; }
    else if (blk < 648)  { src = vwi;   dst = cvt + CVT_VWI;   lb = blk - 264; }
    else if (blk < 1416) { src = ewi;   dst = cvt + CVT_EWI;   lb = blk - 648; }
    else if (blk < 2184) { src = vwh;   dst = cvt + CVT_VWH;   lb = blk - 1416; }
    else if (blk < 2952) { src = ewh;   dst = cvt + CVT_EWH;   lb = blk - 2184; }
    else if (blk < 3464) { src = voutw; dst = cvt + CVT_VOUT;  lb = blk - 2952; }
    else if (blk < 3528) { src = vrepw; dst = cvt + CVT_VREPW; lb = blk - 3464; }
    else                 { src = erepw; dst = cvt + CVT_EREPW; lb = blk - 3528; }
    int idx = lb * 1024 + threadIdx.x * 4;
    float4 v = *(const float4*)(src + idx);
    bf16x4 o;
    o[0] = (bf16_t)v.x; o[1] = (bf16_t)v.y; o[2] = (bf16_t)v.z; o[3] = (bf16_t)v.w;
    *(bf16x4*)(dst + idx) = o;
}

// ---------------------------------------------------------------------------
// Generic C = gather(A) @ W^T + bias GEMM. Wave computes 64x64 (4x4 MFMA tiles).
// GATHER: 0 = dense A[M,K] bf16; 1 = vertex emb gather (K=256); 2 = edge emb pair (K=512)
// OUTMODE: 0 = row-major CT C[row*N+col]; 1 = O_vertex scatter [(b*1024+col)*32+t]
// row m = t*128 + b (t-major), matching [T,B,*] tensors. W is bf16 [N,K]. bias fp32.
// ---------------------------------------------------------------------------
template<int GATHER, int OUTMODE, int K, typename CT>
__global__ __launch_bounds__(256) void gemm_bt(
    const bf16_t* __restrict__ A, const bf16_t* __restrict__ W,
    const float* __restrict__ bias, CT* __restrict__ C,
    const int* __restrict__ gidx, const bf16_t* __restrict__ emb, int N)
{
    constexpr int K32 = K / 32;
    const int tid = threadIdx.x, lane = tid & 63, wv = tid >> 6;
    const int r16 = lane & 15, quad = lane >> 4, koff = quad * 8;
    const int mbase = blockIdx.x * 256 + wv * 64;
    const int nbase = blockIdx.y * 64;

    const bf16_t* ap0[4];
    const bf16_t* ap1[4];
#pragma unroll
    for (int i = 0; i < 4; ++i) {
        int row = mbase + i * 16 + r16;
        if (GATHER == 0) {
            ap0[i] = A + (size_t)row * K + koff;
            ap1[i] = ap0[i];
        } else if (GATHER == 1) {
            int b = row & 127, t = row >> 7;
            int idx = gidx[b * 32 + t];
            ap0[i] = emb + (size_t)idx * 256 + koff;
            ap1[i] = ap0[i];
        } else {
            int b = row & 127, t = row >> 7;
            int c = (b * 64 + t) * 3;
            ap0[i] = emb + (size_t)gidx[c] * 256 + koff;
            ap1[i] = emb + (size_t)gidx[c + 1] * 256 + koff;
        }
    }
    const bf16_t* bp[4];
#pragma unroll
    for (int j = 0; j < 4; ++j)
        bp[j] = W + (size_t)(nbase + j * 16 + r16) * K + koff;

    f32x4 acc[4][4];
#pragma unroll
    for (int i = 0; i < 4; ++i)
#pragma unroll
        for (int j = 0; j < 4; ++j) acc[i][j] = (f32x4){0.f, 0.f, 0.f, 0.f};

    for (int kc = 0; kc < K32; ++kc) {
        bf16x8 a[4], b[4];
#pragma unroll
        for (int i = 0; i < 4; ++i) {
            const bf16_t* p;
            if (GATHER == 2) p = (kc < 8) ? (ap0[i] + kc * 32) : (ap1[i] + (kc - 8) * 32);
            else             p = ap0[i] + kc * 32;
            a[i] = *(const bf16x8*)p;
        }
#pragma unroll
        for (int j = 0; j < 4; ++j) b[j] = *(const bf16x8*)(bp[j] + kc * 32);
#pragma unroll
        for (int i = 0; i < 4; ++i)
#pragma unroll
            for (int j = 0; j < 4; ++j)
                acc[i][j] = __builtin_amdgcn_mfma_f32_16x16x32_bf16(a[i], b[j], acc[i][j], 0, 0, 0);
    }

#pragma unroll
    for (int j = 0; j < 4; ++j) {
        int col = nbase + j * 16 + r16;
        float bf = bias[col];
#pragma unroll
        for (int i = 0; i < 4; ++i) {
#pragma unroll
            for (int q = 0; q < 4; ++q) {
                int row = mbase + i * 16 + quad * 4 + q;
                float v = acc[i][j][q] + bf;
                if (OUTMODE == 0) {
                    C[(size_t)row * N + col] = (CT)v;
                } else {
                    int b = row & 127, t = row >> 7;
                    C[((size_t)(b * 1024) + col) * 32 + t] = (CT)v;
                }
            }
        }
    }
}

// ---------------------------------------------------------------------------
// Fused GRU scans (vertex blocks 0..31, edge blocks 32..63).
// Block = 512 thr (8 waves). Group = 16 batch rows, 4 blocks (128 h-cols each).
// Wh slice lives in VGPRs (48 b-frags/lane = 192 VGPR). h exchanged per step
// via double-buffered global hbuf + per-group monotone counter barrier.
// ---------------------------------------------------------------------------
__global__ __launch_bounds__(512) void gru_scan(
    const bf16_t* __restrict__ giV, const bf16_t* __restrict__ giE,
    const bf16_t* __restrict__ WhV, const bf16_t* __restrict__ WhE,
    const float* __restrict__ bhV, const float* __restrict__ bhE,
    bf16_t* __restrict__ hV, bf16_t* __restrict__ hE,
    bf16_t* __restrict__ hbuf, int* __restrict__ cnts)
{
    const int blk  = blockIdx.x;
    const int role = blk >> 5;          // 0 vertex, 1 edge
    const int lb   = blk & 31;
    const int g    = lb & 7;            // batch group; group's blocks == g (mod 8) -> XCD locality
    const int s    = lb >> 3;           // col-slice 0..3
    const bf16_t* gi = role ? giE : giV;
    const bf16_t* Wh = role ? WhE : WhV;
    const float*  bh = role ? bhE : bhV;
    bf16_t* hout = role ? hE : hV;
    const int T = role ? 64 : 32;
    const int slot = role * 8 + g;
    bf16_t* buf0 = hbuf + (size_t)slot * 2 * 8192;
    bf16_t* buf1 = buf0 + 8192;
    int* cnt = cnts + slot * 64;
    const int bb = g * 16;

    const int tid = threadIdx.x, lane = tid & 63, wv = tid >> 6;
    const int r16 = lane & 15, quad = lane >> 4, koff = quad * 8;
    const int j = s * 128 + wv * 16 + r16;   // this lane's h column (0..511)

    // --- preload Wh slice into registers: wfrag[gate][kc] ---
    bf16x8 wfrag[3][16];
#pragma unroll
    for (int gate = 0; gate < 3; ++gate) {
        const bf16_t* wrow = Wh + ((size_t)(gate * 512 + j)) * 512 + koff;
#pragma unroll
        for (int kc = 0; kc < 16; ++kc)
            wfrag[gate][kc] = *(const bf16x8*)(wrow + kc * 32);
    }
    const float bhr = bh[j], bhz = bh[512 + j], bhn = bh[1024 + j];
    float hq[4] = {0.f, 0.f, 0.f, 0.f};     // persistent fp32 h for this lane's 4 rows

    __shared__ __align__(16) bf16_t hbf[16][520];   // +8 pad: 2-way bank alias only (free)

    for (int t = 0; t < T; ++t) {
        // phase A: full h(t) -> LDS (16x512 bf16 = 1024 16B chunks)
        const bf16_t* src = (t & 1) ? buf1 : buf0;
#pragma unroll
        for (int it = 0; it < 2; ++it) {
            int f = tid + it * 512;
            int row = f >> 6, col = (f & 63) * 8;
            *(bf16x8*)&hbf[row][col] = *(const bf16x8*)(src + row * 512 + col);
        }
        __syncthreads();

        // phase B: gh tiles for this lane's 16-col strip, all 3 gates
        f32x4 ar = {0.f,0.f,0.f,0.f}, az = {0.f,0.f,0.f,0.f}, an = {0.f,0.f,0.f,0.f};
#pragma unroll
        for (int kc = 0; kc < 16; ++kc) {
            bf16x8 a = *(const bf16x8*)&hbf[r16][kc * 32 + koff];
            ar = __builtin_amdgcn_mfma_f32_16x16x32_bf16(a, wfrag[0][kc], ar, 0, 0, 0);
            az = __builtin_amdgcn_mfma_f32_16x16x32_bf16(a, wfrag[1][kc], az, 0, 0, 0);
            an = __builtin_amdgcn_mfma_f32_16x16x32_bf16(a, wfrag[2][kc], an, 0, 0, 0);
        }

        // phase C: gates + h update (C-frag: col=lane&15, row=quad*4+q)
        bf16_t* dst = (t & 1) ? buf0 : buf1;
#pragma unroll
        for (int q = 0; q < 4; ++q) {
            int row = quad * 4 + q;
            size_t gb = ((size_t)(t * 128 + bb + row)) * 1536 + j;
            float ir = (float)gi[gb], iz = (float)gi[gb + 512], inn = (float)gi[gb + 1024];
            float r = fsigmoid(ir + ar[q] + bhr);
            float z = fsigmoid(iz + az[q] + bhz);
            float n = ftanh(inn + r * (an[q] + bhn));
            float hnew = (1.0f - z) * n + z * hq[q];
            hq[q] = hnew;
            bf16_t hb = (bf16_t)hnew;
            dst[row * 512 + j] = hb;
            hout[((size_t)(t * 128 + bb + row)) * 512 + j] = hb;
        }

        // group barrier (4 blocks), monotone counter
        __threadfence();
        __syncthreads();
        if (tid == 0) {
            __hip_atomic_fetch_add(cnt, 1, __ATOMIC_ACQ_REL, __HIP_MEMORY_SCOPE_AGENT);
            int target = 4 * (t + 1);
            while (__hip_atomic_load(cnt, __ATOMIC_RELAXED, __HIP_MEMORY_SCOPE_AGENT) < target)
                __builtin_amdgcn_s_sleep(1);
        }
        __syncthreads();
        __threadfence();
    }
}

// O_edge_type[b,k,te] = erep[te,b,:] . etype_W[k,:] + etype_b[k]
__global__ __launch_bounds__(256) void etype_kernel(
    const bf16_t* __restrict__ erep, const float* __restrict__ W,
    const float* __restrict__ bias, float* __restrict__ out)
{
    int o = blockIdx.x * 256 + threadIdx.x;      // 65536 outputs
    int te = o & 63, k = (o >> 6) & 7, b = o >> 9;
    float sacc = bias[k];
    const bf16_t* e = erep + ((size_t)(te * 128 + b)) * 128;
    const float* w = W + k * 128;
#pragma unroll 8
    for (int r = 0; r < 128; ++r) sacc += (float)e[r] * w[r];
    out[OUT_OT + o] = sacc;
}

// O_edge[b,tv,{0,1},te] = sum_r tanh(e[te,b,r]+v[tv,b,r]) * {src,dst}_w[r] + {src,dst}_b
__global__ __launch_bounds__(256) void attn_kernel(
    const bf16_t* __restrict__ erep, const bf16_t* __restrict__ vrep,
    const float* __restrict__ src_w, const float* __restrict__ src_b,
    const float* __restrict__ dst_w, const float* __restrict__ dst_b,
    float* __restrict__ out)
{
    int b = blockIdx.x >> 1, half = blockIdx.x & 1;
    __shared__ float es[32][129], vs[32][129], swf[128], dwf[128];
    int tid = threadIdx.x;
    for (int f = tid; f < 32 * 128; f += 256) {
        int i = f >> 7, r = f & 127;
        es[i][r] = (float)erep[((size_t)((half * 32 + i) * 128 + b)) * 128 + r];
        vs[i][r] = (float)vrep[((size_t)(i * 128 + b)) * 128 + r];
    }
    if (tid < 128) { swf[tid] = src_w[tid]; dwf[tid] = dst_w[tid]; }
    __syncthreads();
    float sb = src_b[0], db = dst_b[0];
    for (int p = tid; p < 1024; p += 256) {
        int te = p & 31, tv = p >> 5;
        float sacc = 0.f, dacc = 0.f;
#pragma unroll 4
        for (int r = 0; r < 128; ++r) {
            float u = ftanh(es[te][r] + vs[tv][r]);
            sacc += u * swf[r];
            dacc += u * dwf[r];
        }
        int teg = half * 32 + te;
        size_t base = OUT_OE + ((size_t)(b * 32 + tv) * 2) * 64;
        out[base + teg]      = sacc + sb;
        out[base + 64 + teg] = dacc + db;
    }
}

extern "C" void kernel_launch(void* const* d_in, const int* in_sizes, int n_in,
                              void* d_out, int out_size, void* d_ws, size_t ws_size,
                              hipStream_t stream)
{
    const int*   input_vertex = (const int*)d_in[0];
    const int*   input_edge   = (const int*)d_in[1];
    const float* vertex_emb   = (const float*)d_in[2];
    const float* v_Wi  = (const float*)d_in[3];
    const float* v_Wh  = (const float*)d_in[4];
    const float* v_bi  = (const float*)d_in[5];
    const float* v_bh  = (const float*)d_in[6];
    const float* vout_W = (const float*)d_in[7];
    const float* vout_b = (const float*)d_in[8];
    const float* vrep_W = (const float*)d_in[9];
    const float* vrep_b = (const float*)d_in[10];
    const float* edge_emb = (const float*)d_in[11];
    const float* e_Wi  = (const float*)d_in[12];
    const float* e_Wh  = (const float*)d_in[13];
    const float* e_bi  = (const float*)d_in[14];
    const float* e_bh  = (const float*)d_in[15];
    const float* erep_W = (const float*)d_in[16];
    const float* erep_b = (const float*)d_in[17];
    const float* etype_W = (const float*)d_in[18];
    const float* etype_b = (const float*)d_in[19];
    const float* src_w = (const float*)d_in[20];
    const float* src_b = (const float*)d_in[21];
    const float* dst_w = (const float*)d_in[22];
    const float* dst_b = (const float*)d_in[23];

    bf16_t* ws   = (bf16_t*)d_ws;
    bf16_t* giV  = ws + OFF_GIV;
    bf16_t* giE  = ws + OFF_GIE;
    bf16_t* hV   = ws + OFF_HV;
    bf16_t* hE   = ws + OFF_HE;
    bf16_t* vrep = ws + OFF_VREP;
    bf16_t* erep = ws + OFF_EREP;
    bf16_t* hbuf = ws + OFF_HBUF;
    bf16_t* cvt  = ws + OFF_CVT;
    int*    cnts = (int*)((char*)d_ws + CNT_BYTE_OFF);
    float*  out  = (float*)d_out;

    // downcast weights + zero hbuf/counters
    prep_kernel<<<3721, 256, 0, stream>>>(vertex_emb, edge_emb, v_Wi, e_Wi, v_Wh, e_Wh,
                                          vout_W, vrep_W, erep_W, cvt,
                                          (int*)((char*)d_ws + OFF_HBUF * 2));

    // gi projections (bf16 out)
    gemm_bt<1, 0, 256, bf16_t><<<dim3(16, 24), 256, 0, stream>>>(
        nullptr, cvt + CVT_VWI, v_bi, giV, input_vertex, cvt + CVT_VEMB, 1536);
    gemm_bt<2, 0, 512, bf16_t><<<dim3(32, 24), 256, 0, stream>>>(
        nullptr, cvt + CVT_EWI, e_bi, giE, input_edge, cvt + CVT_EEMB, 1536);

    // fused vertex+edge GRU scans
    gru_scan<<<64, 512, 0, stream>>>(giV, giE, cvt + CVT_VWH, cvt + CVT_EWH,
                                     v_bh, e_bh, hV, hE, hbuf, cnts);

    // output projections
    gemm_bt<0, 1, 512, float><<<dim3(16, 16), 256, 0, stream>>>(
        hV, cvt + CVT_VOUT, vout_b, out, nullptr, nullptr, 1024);
    gemm_bt<0, 0, 512, bf16_t><<<dim3(16, 2), 256, 0, stream>>>(
        hV, cvt + CVT_VREPW, vrep_b, vrep, nullptr, nullptr, 128);
    gemm_bt<0, 0, 512, bf16_t><<<dim3(32, 2), 256, 0, stream>>>(
        hE, cvt + CVT_EREPW, erep_b, erep, nullptr, nullptr, 128);

    etype_kernel<<<256, 256, 0, stream>>>(erep, etype_W, etype_b, out);
    attn_kernel<<<256, 256, 0, stream>>>(erep, vrep, src_w, src_b, dst_w, dst_b, out);
}

// Round 3
// 534.110 us; speedup vs baseline: 2.7256x; 2.7256x over previous
//
#include <hip/hip_runtime.h>
#include <hip/hip_bf16.h>

// ---------------------------------------------------------------------------
// RNN_17214228922840: GraphRNN-ish model. fp32 I/O, bf16 MFMA compute.
//   B=128, TV=32, TE=64, VOCAB=1024, EMB=256, H=512 (3H=1536), REPR=128, NET=8
// Outputs (flat, fp32): O_vertex [128,1024,32] | O_edge [128,32,2,64] | O_edge_type [128,8,64]
// ---------------------------------------------------------------------------

typedef __bf16 bf16_t;
typedef bf16_t bf16x8 __attribute__((ext_vector_type(8)));
typedef bf16_t bf16x4 __attribute__((ext_vector_type(4)));
typedef float  f32x4  __attribute__((ext_vector_type(4)));

// workspace layout (bf16 element offsets)
#define OFF_GIV  0ull                    // 32*128*1536
#define OFF_GIE  6291456ull              // 64*128*1536
#define OFF_HV   18874368ull             // 32*128*512
#define OFF_HE   20971520ull             // 64*128*512
#define OFF_VREP 25165824ull             // 32*128*128
#define OFF_EREP 25690112ull             // 64*128*128
#define OFF_HBUF 26738688ull             // 16 slots * 2 parity * 8192
#define CNT_BYTE_OFF 54001664ull         // 1024 ints (16 counters, 64 apart)
#define OFF_CVT  27002880ull             // converted bf16 weights below
#define CVT_VEMB  0ull
#define CVT_EEMB  262144ull
#define CVT_VWI   270336ull
#define CVT_EWI   663552ull
#define CVT_VWH   1449984ull
#define CVT_EWH   2236416ull
#define CVT_VOUT  3022848ull
#define CVT_VREPW 3547136ull
#define CVT_EREPW 3612672ull

// output flat offsets (fp32 elements)
#define OUT_OV 0ull
#define OUT_OE 4194304ull
#define OUT_OT 4718592ull

__device__ __forceinline__ float fsigmoid(float x) {
    float e = __builtin_amdgcn_exp2f(-x * 1.4426950408889634f);
    return __builtin_amdgcn_rcpf(1.0f + e);
}
__device__ __forceinline__ float ftanh(float x) {
    x = fminf(x, 15.0f);
    float e = __builtin_amdgcn_exp2f(x * 2.8853900817779268f); // exp(2x)
    return (e - 1.0f) * __builtin_amdgcn_rcpf(e + 1.0f);
}

// ---------------------------------------------------------------------------
// prep: fp32 -> bf16 downcast of weights/embeddings (blocks 0..3591, 1024 elem
// per block) + zero hbuf/counters (blocks 3592..3720, 1024 ints per block).
// ---------------------------------------------------------------------------
__global__ __launch_bounds__(256) void prep_kernel(
    const float* __restrict__ vemb, const float* __restrict__ eemb,
    const float* __restrict__ vwi,  const float* __restrict__ ewi,
    const float* __restrict__ vwh,  const float* __restrict__ ewh,
    const float* __restrict__ voutw, const float* __restrict__ vrepw,
    const float* __restrict__ erepw, bf16_t* __restrict__ cvt,
    int* __restrict__ zero_base)
{
    int blk = blockIdx.x;
    if (blk >= 3592) {
        ((int4*)zero_base)[(blk - 3592) * 256 + threadIdx.x] = (int4){0, 0, 0, 0};
        return;
    }
    const float* src; bf16_t* dst; int lb;
    if (blk < 256)       { src = vemb;  dst = cvt + CVT_VEMB;  lb = blk; }
    else if (blk < 264)  { src = eemb;  dst = cvt + CVT_EEMB;  lb = blk - 256; }
    else if (blk < 648)  { src = vwi;   dst = cvt + CVT_VWI;   lb = blk - 264; }
    else if (blk < 1416) { src = ewi;   dst = cvt + CVT_EWI;   lb = blk - 648; }
    else if (blk < 2184) { src = vwh;   dst = cvt + CVT_VWH;   lb = blk - 1416; }
    else if (blk < 2952) { src = ewh;   dst = cvt + CVT_EWH;   lb = blk - 2184; }
    else if (blk < 3464) { src = voutw; dst = cvt + CVT_VOUT;  lb = blk - 2952; }
    else if (blk < 3528) { src = vrepw; dst = cvt + CVT_VREPW; lb = blk - 3464; }
    else                 { src = erepw; dst = cvt + CVT_EREPW; lb = blk - 3528; }
    int idx = lb * 1024 + threadIdx.x * 4;
    float4 v = *(const float4*)(src + idx);
    bf16x4 o;
    o[0] = (bf16_t)v.x; o[1] = (bf16_t)v.y; o[2] = (bf16_t)v.z; o[3] = (bf16_t)v.w;
    *(bf16x4*)(dst + idx) = o;
}

// ---------------------------------------------------------------------------
// Generic C = gather(A) @ W^T + bias GEMM. Wave computes 64x64 (4x4 MFMA tiles).
// ---------------------------------------------------------------------------
template<int GATHER, int OUTMODE, int K, typename CT>
__global__ __launch_bounds__(256) void gemm_bt(
    const bf16_t* __restrict__ A, const bf16_t* __restrict__ W,
    const float* __restrict__ bias, CT* __restrict__ C,
    const int* __restrict__ gidx, const bf16_t* __restrict__ emb, int N)
{
    constexpr int K32 = K / 32;
    const int tid = threadIdx.x, lane = tid & 63, wv = tid >> 6;
    const int r16 = lane & 15, quad = lane >> 4, koff = quad * 8;
    const int mbase = blockIdx.x * 256 + wv * 64;
    const int nbase = blockIdx.y * 64;

    const bf16_t* ap0[4];
    const bf16_t* ap1[4];
#pragma unroll
    for (int i = 0; i < 4; ++i) {
        int row = mbase + i * 16 + r16;
        if (GATHER == 0) {
            ap0[i] = A + (size_t)row * K + koff;
            ap1[i] = ap0[i];
        } else if (GATHER == 1) {
            int b = row & 127, t = row >> 7;
            int idx = gidx[b * 32 + t];
            ap0[i] = emb + (size_t)idx * 256 + koff;
            ap1[i] = ap0[i];
        } else {
            int b = row & 127, t = row >> 7;
            int c = (b * 64 + t) * 3;
            ap0[i] = emb + (size_t)gidx[c] * 256 + koff;
            ap1[i] = emb + (size_t)gidx[c + 1] * 256 + koff;
        }
    }
    const bf16_t* bp[4];
#pragma unroll
    for (int j = 0; j < 4; ++j)
        bp[j] = W + (size_t)(nbase + j * 16 + r16) * K + koff;

    f32x4 acc[4][4];
#pragma unroll
    for (int i = 0; i < 4; ++i)
#pragma unroll
        for (int j = 0; j < 4; ++j) acc[i][j] = (f32x4){0.f, 0.f, 0.f, 0.f};

    for (int kc = 0; kc < K32; ++kc) {
        bf16x8 a[4], b[4];
#pragma unroll
        for (int i = 0; i < 4; ++i) {
            const bf16_t* p;
            if (GATHER == 2) p = (kc < 8) ? (ap0[i] + kc * 32) : (ap1[i] + (kc - 8) * 32);
            else             p = ap0[i] + kc * 32;
            a[i] = *(const bf16x8*)p;
        }
#pragma unroll
        for (int j = 0; j < 4; ++j) b[j] = *(const bf16x8*)(bp[j] + kc * 32);
#pragma unroll
        for (int i = 0; i < 4; ++i)
#pragma unroll
            for (int j = 0; j < 4; ++j)
                acc[i][j] = __builtin_amdgcn_mfma_f32_16x16x32_bf16(a[i], b[j], acc[i][j], 0, 0, 0);
    }

#pragma unroll
    for (int j = 0; j < 4; ++j) {
        int col = nbase + j * 16 + r16;
        float bf = bias[col];
#pragma unroll
        for (int i = 0; i < 4; ++i) {
#pragma unroll
            for (int q = 0; q < 4; ++q) {
                int row = mbase + i * 16 + quad * 4 + q;
                float v = acc[i][j][q] + bf;
                if (OUTMODE == 0) {
                    C[(size_t)row * N + col] = (CT)v;
                } else {
                    int b = row & 127, t = row >> 7;
                    C[((size_t)(b * 1024) + col) * 32 + t] = (CT)v;
                }
            }
        }
    }
}

// ---------------------------------------------------------------------------
// Fused GRU scans (vertex blocks 0..31, edge blocks 32..63).
// Block = 512 thr (8 waves). Group = 16 batch rows, 4 blocks (128 h-cols each).
// Wh slice lives in VGPRs (192 VGPR/lane; launch_bounds(512,2) -> 256 cap, no
// spill). h exchanged per step via double-buffered global hbuf accessed with
// RELAXED AGENT-scope atomics (sc0 sc1 -> device coherence point; NO
// threadfence/wbl2). Ordering: stores -> s_waitcnt(0) -> block barrier ->
// tid0 relaxed atomic add + poll -> block barrier.
// ---------------------------------------------------------------------------
__global__ __launch_bounds__(512, 2) void gru_scan(
    const bf16_t* __restrict__ giV, const bf16_t* __restrict__ giE,
    const bf16_t* __restrict__ WhV, const bf16_t* __restrict__ WhE,
    const float* __restrict__ bhV, const float* __restrict__ bhE,
    bf16_t* __restrict__ hV, bf16_t* __restrict__ hE,
    bf16_t* __restrict__ hbuf, int* __restrict__ cnts)
{
    const int blk  = blockIdx.x;
    const int role = blk >> 5;          // 0 vertex, 1 edge
    const int lb   = blk & 31;
    const int g    = lb & 7;            // batch group
    const int s    = lb >> 3;           // col-slice 0..3
    const bf16_t* gi = role ? giE : giV;
    const bf16_t* Wh = role ? WhE : WhV;
    const float*  bh = role ? bhE : bhV;
    bf16_t* hout = role ? hE : hV;
    const int T = role ? 64 : 32;
    const int slot = role * 8 + g;
    bf16_t* buf0 = hbuf + (size_t)slot * 2 * 8192;
    bf16_t* buf1 = buf0 + 8192;
    int* cnt = cnts + slot * 64;
    const int bb = g * 16;

    const int tid = threadIdx.x, lane = tid & 63, wv = tid >> 6;
    const int r16 = lane & 15, quad = lane >> 4, koff = quad * 8;
    const int j = s * 128 + wv * 16 + r16;   // this lane's h column (0..511)

    // --- preload Wh slice into registers: wfrag[gate][kc] (192 VGPRs) ---
    bf16x8 wfrag[3][16];
#pragma unroll
    for (int gate = 0; gate < 3; ++gate) {
        const bf16_t* wrow = Wh + ((size_t)(gate * 512 + j)) * 512 + koff;
#pragma unroll
        for (int kc = 0; kc < 16; ++kc)
            wfrag[gate][kc] = *(const bf16x8*)(wrow + kc * 32);
    }
    const float bhr = bh[j], bhz = bh[512 + j], bhn = bh[1024 + j];
    float hq[4] = {0.f, 0.f, 0.f, 0.f};

    __shared__ __align__(16) bf16_t hbf[16][520];   // +8 pad

    for (int t = 0; t < T; ++t) {
        // prefetch this step's gi values (independent of the barrier)
        bf16_t gpre[12];
#pragma unroll
        for (int q = 0; q < 4; ++q) {
            size_t gb = ((size_t)(t * 128 + bb + quad * 4 + q)) * 1536 + j;
            gpre[q * 3 + 0] = gi[gb];
            gpre[q * 3 + 1] = gi[gb + 512];
            gpre[q * 3 + 2] = gi[gb + 1024];
        }

        // phase A: h(t) [16x512 bf16] from hbuf -> LDS via 8B agent-scope loads
        {
            unsigned long long* src = (unsigned long long*)((t & 1) ? buf1 : buf0);
#pragma unroll
            for (int it = 0; it < 4; ++it) {
                int c = tid + it * 512;             // 2048 8B units
                int row = c >> 7, unit = c & 127;
                unsigned long long v = __hip_atomic_load(src + c, __ATOMIC_RELAXED,
                                                         __HIP_MEMORY_SCOPE_AGENT);
                *(unsigned long long*)&hbf[row][unit * 4] = v;
            }
        }
        __syncthreads();

        // phase B: gh for this lane's 16-col strip, 3 gates
        f32x4 ar = {0.f,0.f,0.f,0.f}, az = {0.f,0.f,0.f,0.f}, an = {0.f,0.f,0.f,0.f};
#pragma unroll
        for (int kc = 0; kc < 16; ++kc) {
            bf16x8 a = *(const bf16x8*)&hbf[r16][kc * 32 + koff];
            ar = __builtin_amdgcn_mfma_f32_16x16x32_bf16(a, wfrag[0][kc], ar, 0, 0, 0);
            az = __builtin_amdgcn_mfma_f32_16x16x32_bf16(a, wfrag[1][kc], az, 0, 0, 0);
            an = __builtin_amdgcn_mfma_f32_16x16x32_bf16(a, wfrag[2][kc], an, 0, 0, 0);
        }

        // phase C: gates + h update (C-frag: col=lane&15, row=quad*4+q)
        bf16_t* dst = (t & 1) ? buf0 : buf1;
#pragma unroll
        for (int q = 0; q < 4; ++q) {
            int row = quad * 4 + q;
            float ir = (float)gpre[q * 3 + 0];
            float iz = (float)gpre[q * 3 + 1];
            float inn = (float)gpre[q * 3 + 2];
            float r = fsigmoid(ir + ar[q] + bhr);
            float z = fsigmoid(iz + az[q] + bhz);
            float n = ftanh(inn + r * (an[q] + bhn));
            float hnew = (1.0f - z) * n + z * hq[q];
            hq[q] = hnew;
            bf16_t hb = (bf16_t)hnew;
            __hip_atomic_store((unsigned short*)(dst + row * 512 + j),
                               __builtin_bit_cast(unsigned short, hb),
                               __ATOMIC_RELAXED, __HIP_MEMORY_SCOPE_AGENT);
            hout[((size_t)(t * 128 + bb + row)) * 512 + j] = hb;
        }

        // group barrier (4 blocks), monotone counter; skip after last step
        if (t + 1 < T) {
            __builtin_amdgcn_s_waitcnt(0);          // drain h stores (acks at MALL)
            asm volatile("" ::: "memory");
            __syncthreads();                        // whole block's stores drained
            if (tid == 0) {
                __hip_atomic_fetch_add(cnt, 1, __ATOMIC_RELAXED, __HIP_MEMORY_SCOPE_AGENT);
                int target = 4 * (t + 1);
                while (__hip_atomic_load(cnt, __ATOMIC_RELAXED, __HIP_MEMORY_SCOPE_AGENT) < target)
                    __builtin_amdgcn_s_sleep(2);
            }
            __syncthreads();
            asm volatile("" ::: "memory");
        }
    }
}

// O_edge_type[b,k,te] = erep[te,b,:] . etype_W[k,:] + etype_b[k]
__global__ __launch_bounds__(256) void etype_kernel(
    const bf16_t* __restrict__ erep, const float* __restrict__ W,
    const float* __restrict__ bias, float* __restrict__ out)
{
    int o = blockIdx.x * 256 + threadIdx.x;      // 65536 outputs
    int te = o & 63, k = (o >> 6) & 7, b = o >> 9;
    float sacc = bias[k];
    const bf16_t* e = erep + ((size_t)(te * 128 + b)) * 128;
    const float* w = W + k * 128;
#pragma unroll 8
    for (int r = 0; r < 128; ++r) sacc += (float)e[r] * w[r];
    out[OUT_OT + o] = sacc;
}

// O_edge[b,tv,{0,1},te] = sum_r tanh(e[te,b,r]+v[tv,b,r]) * {src,dst}_w[r] + {src,dst}_b
__global__ __launch_bounds__(256) void attn_kernel(
    const bf16_t* __restrict__ erep, const bf16_t* __restrict__ vrep,
    const float* __restrict__ src_w, const float* __restrict__ src_b,
    const float* __restrict__ dst_w, const float* __restrict__ dst_b,
    float* __restrict__ out)
{
    int b = blockIdx.x >> 1, half = blockIdx.x & 1;
    __shared__ float es[32][129], vs[32][129], swf[128], dwf[128];
    int tid = threadIdx.x;
    for (int f = tid; f < 32 * 128; f += 256) {
        int i = f >> 7, r = f & 127;
        es[i][r] = (float)erep[((size_t)((half * 32 + i) * 128 + b)) * 128 + r];
        vs[i][r] = (float)vrep[((size_t)(i * 128 + b)) * 128 + r];
    }
    if (tid < 128) { swf[tid] = src_w[tid]; dwf[tid] = dst_w[tid]; }
    __syncthreads();
    float sb = src_b[0], db = dst_b[0];
    for (int p = tid; p < 1024; p += 256) {
        int te = p & 31, tv = p >> 5;
        float sacc = 0.f, dacc = 0.f;
#pragma unroll 4
        for (int r = 0; r < 128; ++r) {
            float u = ftanh(es[te][r] + vs[tv][r]);
            sacc += u * swf[r];
            dacc += u * dwf[r];
        }
        int teg = half * 32 + te;
        size_t base = OUT_OE + ((size_t)(b * 32 + tv) * 2) * 64;
        out[base + teg]      = sacc + sb;
        out[base + 64 + teg] = dacc + db;
    }
}

extern "C" void kernel_launch(void* const* d_in, const int* in_sizes, int n_in,
                              void* d_out, int out_size, void* d_ws, size_t ws_size,
                              hipStream_t stream)
{
    const int*   input_vertex = (const int*)d_in[0];
    const int*   input_edge   = (const int*)d_in[1];
    const float* vertex_emb   = (const float*)d_in[2];
    const float* v_Wi  = (const float*)d_in[3];
    const float* v_Wh  = (const float*)d_in[4];
    const float* v_bi  = (const float*)d_in[5];
    const float* v_bh  = (const float*)d_in[6];
    const float* vout_W = (const float*)d_in[7];
    const float* vout_b = (const float*)d_in[8];
    const float* vrep_W = (const float*)d_in[9];
    const float* vrep_b = (const float*)d_in[10];
    const float* edge_emb = (const float*)d_in[11];
    const float* e_Wi  = (const float*)d_in[12];
    const float* e_Wh  = (const float*)d_in[13];
    const float* e_bi  = (const float*)d_in[14];
    const float* e_bh  = (const float*)d_in[15];
    const float* erep_W = (const float*)d_in[16];
    const float* erep_b = (const float*)d_in[17];
    const float* etype_W = (const float*)d_in[18];
    const float* etype_b = (const float*)d_in[19];
    const float* src_w = (const float*)d_in[20];
    const float* src_b = (const float*)d_in[21];
    const float* dst_w = (const float*)d_in[22];
    const float* dst_b = (const float*)d_in[23];

    bf16_t* ws   = (bf16_t*)d_ws;
    bf16_t* giV  = ws + OFF_GIV;
    bf16_t* giE  = ws + OFF_GIE;
    bf16_t* hV   = ws + OFF_HV;
    bf16_t* hE   = ws + OFF_HE;
    bf16_t* vrep = ws + OFF_VREP;
    bf16_t* erep = ws + OFF_EREP;
    bf16_t* hbuf = ws + OFF_HBUF;
    bf16_t* cvt  = ws + OFF_CVT;
    int*    cnts = (int*)((char*)d_ws + CNT_BYTE_OFF);
    float*  out  = (float*)d_out;

    // downcast weights + zero hbuf/counters
    prep_kernel<<<3721, 256, 0, stream>>>(vertex_emb, edge_emb, v_Wi, e_Wi, v_Wh, e_Wh,
                                          vout_W, vrep_W, erep_W, cvt,
                                          (int*)((char*)d_ws + OFF_HBUF * 2));

    // gi projections (bf16 out)
    gemm_bt<1, 0, 256, bf16_t><<<dim3(16, 24), 256, 0, stream>>>(
        nullptr, cvt + CVT_VWI, v_bi, giV, input_vertex, cvt + CVT_VEMB, 1536);
    gemm_bt<2, 0, 512, bf16_t><<<dim3(32, 24), 256, 0, stream>>>(
        nullptr, cvt + CVT_EWI, e_bi, giE, input_edge, cvt + CVT_EEMB, 1536);

    // fused vertex+edge GRU scans
    gru_scan<<<64, 512, 0, stream>>>(giV, giE, cvt + CVT_VWH, cvt + CVT_EWH,
                                     v_bh, e_bh, hV, hE, hbuf, cnts);

    // output projections
    gemm_bt<0, 1, 512, float><<<dim3(16, 16), 256, 0, stream>>>(
        hV, cvt + CVT_VOUT, vout_b, out, nullptr, nullptr, 1024);
    gemm_bt<0, 0, 512, bf16_t><<<dim3(16, 2), 256, 0, stream>>>(
        hV, cvt + CVT_VREPW, vrep_b, vrep, nullptr, nullptr, 128);
    gemm_bt<0, 0, 512, bf16_t><<<dim3(32, 2), 256, 0, stream>>>(
        hE, cvt + CVT_EREPW, erep_b, erep, nullptr, nullptr, 128);

    etype_kernel<<<256, 256, 0, stream>>>(erep, etype_W, etype_b, out);
    attn_kernel<<<256, 256, 0, stream>>>(erep, vrep, src_w, src_b, dst_w, dst_b, out);
}